// Round 7
// baseline (209.049 us; speedup 1.0000x reference)
//
#include <hip/hip_runtime.h>
#include <hip/hip_bf16.h>

// Problem constants
#define NROWS 262144
#define HISTC 24
#define FOREC 20

// MFMA fragment vector types (gfx950 16x16x32 bf16: v8bf16 in, v4f32 acc)
typedef __bf16        v8bf __attribute__((ext_vector_type(8)));
typedef float         v4f  __attribute__((ext_vector_type(4)));
typedef float         v2f  __attribute__((ext_vector_type(2)));
typedef unsigned int  v4u  __attribute__((ext_vector_type(4)));
typedef unsigned int  v2u  __attribute__((ext_vector_type(2)));

// Workspace layout (bytes): [0..16) scalars a,b,g,lam ; then swizzled bf16 weights.
// Swizzle: block (ntile,ktile) of 64 lanes x 8 bf16, elem ((nt*KT+kt)*64 + lane)*8 + j
// holding W^T[feat = nt*16 + (lane&15)][k = kt*32 + (lane>>4)*8 + j]  (OOB -> 0).
// WT4 is REPLICATED to 16 nt-slots (real nt = slot&1) so the generic cross-layer
// prefetch index ((w*4+ft)*8+kt) is valid for layer 4 too.
#define WS_WT1_OFF 64
#define WT1_ELEMS 16384    /* 16 nt * 2 kt * 512 */
#define WT2_ELEMS 65536    /* 16 nt * 8 kt * 512 */
#define WT3_ELEMS 65536
#define WT4R_ELEMS 65536   /* 16 nt-slots (real nt = slot&1) * 8 kt * 512 */

// 2*log2(e): tanh(y) = 1 - 2/(exp2(y*2log2e)+1)
#define TANH_C 2.885390081777927f

__device__ __forceinline__ unsigned short f2bf(float x) {
    unsigned u = __builtin_bit_cast(unsigned, x);
    u += 0x7FFFu + ((u >> 16) & 1u);          // round-to-nearest-even
    return (unsigned short)(u >> 16);
}

// pack two fp32 -> bf16x2 with round-half-up: 2 adds + 1 v_perm.
__device__ __forceinline__ unsigned packbf2(float a, float b) {
    unsigned ua = __builtin_bit_cast(unsigned, a) + 0x8000u;
    unsigned ub = __builtin_bit_cast(unsigned, b) + 0x8000u;
    return __builtin_amdgcn_perm(ub, ua, 0x07060302u);
}

// Barrier with LDS-visibility only: does NOT drain vmcnt, so in-flight global
// (weight-prefetch) loads survive the barrier.
__device__ __forceinline__ void lds_barrier() {
    asm volatile("s_waitcnt lgkmcnt(0)\n\ts_barrier" ::: "memory");
}

// ---------------- prep: scalars + weight transpose/convert/swizzle ----------------
// 8 elems/thread, 16B stores. 212992 elems = 104 blocks; block 104 does scalars.
__global__ void prep_kernel(const float* __restrict__ w1, const float* __restrict__ w2,
                            const float* __restrict__ w3, const float* __restrict__ w4,
                            const float* __restrict__ alpha, const float* __restrict__ beta,
                            const float* __restrict__ gamma, const float* __restrict__ lmix,
                            unsigned char* __restrict__ ws)
{
    if (blockIdx.x == 104) {                    // scalar block
        int t = threadIdx.x;
        float* wsf = (float*)ws;
        if (t == 0) wsf[0] = 1.0f / (1.0f + expf(-alpha[0]));
        else if (t == 1) wsf[1] = 1.0f / (1.0f + expf(-beta[0]));
        else if (t == 2) wsf[2] = fabsf(gamma[0]);
        else if (t == 3) wsf[3] = 1.0f / (1.0f + expf(-lmix[0]));
        return;
    }
    int idx = (blockIdx.x * 256 + threadIdx.x) * 8;   // elem base, 8 per thread
    const float* src;
    int KT, Kreal, Nreal, srcN, local, ntmask;
    unsigned short* dst = (unsigned short*)(ws + WS_WT1_OFF);
    if (idx < WT1_ELEMS) {
        local = idx; src = w1; KT = 2; Kreal = 44; Nreal = 256; srcN = 256; ntmask = 255;
    } else if (idx < WT1_ELEMS + WT2_ELEMS) {
        local = idx - WT1_ELEMS; dst += WT1_ELEMS;
        src = w2; KT = 8; Kreal = 256; Nreal = 256; srcN = 256; ntmask = 255;
    } else if (idx < WT1_ELEMS + WT2_ELEMS + WT3_ELEMS) {
        local = idx - (WT1_ELEMS + WT2_ELEMS); dst += WT1_ELEMS + WT2_ELEMS;
        src = w3; KT = 8; Kreal = 256; Nreal = 256; srcN = 256; ntmask = 255;
    } else {
        local = idx - (WT1_ELEMS + WT2_ELEMS + WT3_ELEMS);
        dst += WT1_ELEMS + WT2_ELEMS + WT3_ELEMS;
        src = w4; KT = 8; Kreal = 256; Nreal = 20; srcN = 20; ntmask = 1;  // replicate
    }
    int L   = (local >> 3) & 63;
    int blk = local >> 9;
    int kt = blk % KT, nt = (blk / KT) & ntmask;
    int cc = L & 15,  qq = L >> 4;
    int feat = nt * 16 + cc;
    int kbase = kt * 32 + qq * 8;
    unsigned short tmp[8];
#pragma unroll
    for (int j = 0; j < 8; ++j) {
        int k = kbase + j;
        float v = (k < Kreal && feat < Nreal) ? src[k * srcN + feat] : 0.0f;
        tmp[j] = f2bf(v);
    }
    v4u pk;
    pk[0] = tmp[0] | ((unsigned)tmp[1] << 16);
    pk[1] = tmp[2] | ((unsigned)tmp[3] << 16);
    pk[2] = tmp[4] | ((unsigned)tmp[5] << 16);
    pk[3] = tmp[6] | ((unsigned)tmp[7] << 16);
    *(v4u*)&dst[local] = pk;
}

// ---------------- fused main kernel ----------------
// 4 waves, 64 samples/block. Wave w: 4 ftiles (features w*64..+63) x 4 stiles.
// Weight frags pipelined distance-1 through a 2-slot buffer A[2][4] (32 VGPR,
// down from 48: unified regs ~120 <= 128 -> 4 waves/SIMD, 4 blocks/CU).
// Every layer enters with its kt0 frags in slot 0; the last kt iteration
// prefetches the NEXT layer's kt0 into slot 0, in flight across tanh + both
// lgkm-only barriers.
template<int KT, int KTN>
__device__ __forceinline__ void layer_pipe(unsigned short* buf,
        const v4u* __restrict__ wp, const v4u* __restrict__ wpn,
        const float* __restrict__ bias, v4u A[2][4],
        int w, int c, int q, int lane)
{
    v4f acc[4][4];
#pragma unroll
    for (int ft = 0; ft < 4; ++ft)
#pragma unroll
        for (int st = 0; st < 4; ++st) {
            v4f z = {0.0f, 0.0f, 0.0f, 0.0f};
            acc[ft][st] = z;
        }

#pragma unroll
    for (int kt = 0; kt < KT; ++kt) {
        const int cs = kt & 1;
        const int ps = cs ^ 1;
        if (kt + 1 < KT) {
#pragma unroll
            for (int ft = 0; ft < 4; ++ft)
                A[ps][ft] = wp[((w * 4 + ft) * KT + kt + 1) * 64 + lane];
        } else {   // prefetch next layer's kt0 (lands in slot (KT)&1... = slot 0 for even KT)
#pragma unroll
            for (int ft = 0; ft < 4; ++ft)
                A[ps][ft] = wpn[((w * 4 + ft) * KTN + 0) * 64 + lane];
        }
#pragma unroll
        for (int st = 0; st < 4; ++st) {
            v4u braw = *(const v4u*)&buf[(st * 16 + c) * 264 + kt * 32 + q * 8];
            v8bf bb = __builtin_bit_cast(v8bf, braw);
#pragma unroll
            for (int ft = 0; ft < 4; ++ft)
                acc[ft][st] = __builtin_amdgcn_mfma_f32_16x16x32_bf16(
                    __builtin_bit_cast(v8bf, A[cs][ft]), bb, acc[ft][st], 0, 0, 0);
        }
    }

    lds_barrier();   // all reads done before in-place overwrite (vmcnt NOT drained)

    // Epilogue: lane (q,c) holds sample c, features base+q*4..+3 per tile.
    // tanh(acc+bi) = tanh-core(acc*C + bi*C): bias folded into the scale fma.
#pragma unroll
    for (int ft = 0; ft < 4; ++ft) {
        v4f bi = *(const v4f*)&bias[w * 64 + ft * 16 + q * 4];
        v4f bic;
#pragma unroll
        for (int r = 0; r < 4; ++r) bic[r] = bi[r] * TANH_C;
#pragma unroll
        for (int st = 0; st < 4; ++st) {
            float x[4];
#pragma unroll
            for (int r = 0; r < 4; ++r) {
                float t = __builtin_fmaf(acc[ft][st][r], TANH_C, bic[r]);
                float p = __builtin_amdgcn_exp2f(t);
                float rc = __builtin_amdgcn_rcpf(p + 1.0f);
                x[r] = __builtin_fmaf(-2.0f, rc, 1.0f);
            }
            v2u d; d[0] = packbf2(x[0], x[1]); d[1] = packbf2(x[2], x[3]);
            *(v2u*)&buf[(st * 16 + c) * 264 + w * 64 + ft * 16 + q * 4] = d;
        }
    }
    lds_barrier();
}

__global__ __launch_bounds__(256, 4) void fused_kernel(
    const float* __restrict__ history,
    const float* __restrict__ eb1, const float* __restrict__ eb2,
    const float* __restrict__ cb1, const float* __restrict__ cb2,
    const unsigned char* __restrict__ ws, float* __restrict__ out)
{
    __shared__ unsigned short buf[64 * 264];   // 33792 B, in-place act buffer
    __shared__ float tp[64 * 20];              // 5120 B fp32 T_physics

    const int tid  = threadIdx.x;
    const int w    = tid >> 6;                 // 4 waves
    const int lane = tid & 63;
    const int c    = lane & 15;
    const int q    = lane >> 4;
    const int row0 = blockIdx.x << 6;          // 64 samples per WG
    const float* wsf = (const float*)ws;
    const v4u* wp1 = (const v4u*)(ws + WS_WT1_OFF);
    const v4u* wp2 = wp1 + WT1_ELEMS / 8;
    const v4u* wp3 = wp2 + WT2_ELEMS / 8;
    const v4u* wp4 = wp3 + WT3_ELEMS / 8;

    // Preload layer-1 kt0 frags into slot 0 BEFORE staging (overlaps L2 latency).
    v4u A[2][4];
#pragma unroll
    for (int ft = 0; ft < 4; ++ft)
        A[0][ft] = wp1[((w * 4 + ft) * 2 + 0) * 64 + lane];

    // --- staging: global float4 -> bf16x4 pack in regs -> one ds_write_b64 ---
#pragma unroll
    for (int i = 0; i < 2; ++i) {
        int e = tid + i * 256;
        if (e < 384) {
            int r  = e / 6, c4 = e - r * 6;
            v4f h4 = *(const v4f*)&history[(long)(row0 + r) * 24 + c4 * 4];
            v2u d; d[0] = packbf2(h4[0], h4[1]); d[1] = packbf2(h4[2], h4[3]);
            *(v2u*)&buf[r * 264 + c4 * 4] = d;
        }
    }
    // zero-fill cols 44..63 (pad vs stale LDS): 64 rows x 5 b64-groups = 320 tasks
#pragma unroll
    for (int i = 0; i < 2; ++i) {
        int e = tid + i * 256;
        if (e < 320) {
            int r = e / 5, g = e - r * 5;
            v2u z = {0u, 0u};
            *(v2u*)&buf[r * 264 + 44 + g * 4] = z;
        }
    }
    // physics: one thread per row; last-6 history read direct from global (L2-hot)
    if (tid < 64) {
        const float* hrow = &history[(long)(row0 + tid) * 24];
        v2f h18 = *(const v2f*)&hrow[18];
        v4f h20 = *(const v4f*)&hrow[20];
        float pa = wsf[0], pb = wsf[1], pg = wsf[2];
        float d0 = h18[0], d1 = h18[1], d2 = h20[0];
        float d3 = h20[1], d4 = h20[2], d5 = h20[3];
        float T = d5;
#pragma unroll
        for (int s = 0; s < 20; ++s) {
            float t3 = T * T * T;
            float Tn = T - pa * T;
            Tn = Tn - pb * d0;
            Tn = Tn - pg * t3;
            tp[tid * 20 + s] = Tn;
            buf[tid * 264 + 24 + s] = f2bf(Tn);
            d0 = d1; d1 = d2; d2 = d3; d3 = d4; d4 = d5; d5 = Tn;
            T = Tn;
        }
    }
    lds_barrier();

    layer_pipe<2, 8>(buf, wp1, wp2, eb1, A, w, c, q, lane);   // 44(pad64)->256
    layer_pipe<8, 8>(buf, wp2, wp3, eb2, A, w, c, q, lane);   // 256->256
    layer_pipe<8, 8>(buf, wp3, wp4, cb1, A, w, c, q, lane);   // 256->256

    // Layer 4: 256 -> 20. Wave w = stile w. Slot 0 holds wp4 kt0 frags
    // (replicated wt4: slot index w*4+ft has real nt = (w*4+ft)&1 = ft&1).
    v4f acc40 = {0.0f, 0.0f, 0.0f, 0.0f}, acc41 = {0.0f, 0.0f, 0.0f, 0.0f};
#pragma unroll
    for (int kt = 0; kt < 8; ++kt) {
        const int cs = kt & 1, ps = cs ^ 1;
        if (kt + 1 < 8) {
            A[ps][0] = wp4[((w * 4 + 0) * 8 + kt + 1) * 64 + lane];
            A[ps][1] = wp4[((w * 4 + 1) * 8 + kt + 1) * 64 + lane];
        }
        v4u braw = *(const v4u*)&buf[(w * 16 + c) * 264 + kt * 32 + q * 8];
        v8bf bb = __builtin_bit_cast(v8bf, braw);
        acc40 = __builtin_amdgcn_mfma_f32_16x16x32_bf16(
            __builtin_bit_cast(v8bf, A[cs][0]), bb, acc40, 0, 0, 0);
        acc41 = __builtin_amdgcn_mfma_f32_16x16x32_bf16(
            __builtin_bit_cast(v8bf, A[cs][1]), bb, acc41, 0, 0, 0);
    }

    const float lam = wsf[3];
    const long sample = (long)row0 + w * 16 + c;
    float* outP = out;                         // T_pred
    float* outF = out + (long)NROWS * 20;      // T_physics
    float* outS = out + (long)NROWS * 40;      // T_soft
    {   // ftile 0: features q*4..q*4+3, all valid (<20)
        int f0 = q * 4;
        v4f bi  = *(const v4f*)&cb2[f0];
        v4f tph = *(const v4f*)&tp[(w * 16 + c) * 20 + f0];
        v4f ts, pr;
#pragma unroll
        for (int r = 0; r < 4; ++r) {
            ts[r] = acc40[r] + bi[r];
            pr[r] = tph[r] + lam * ts[r];
        }
        *(v4f*)&outS[sample * 20 + f0] = ts;
        *(v4f*)&outP[sample * 20 + f0] = pr;
        *(v4f*)&outF[sample * 20 + f0] = tph;
    }
    if (q == 0) {  // ftile 1: features 16..19 valid only for q==0
        v4f bi  = *(const v4f*)&cb2[16];
        v4f tph = *(const v4f*)&tp[(w * 16 + c) * 20 + 16];
        v4f ts, pr;
#pragma unroll
        for (int r = 0; r < 4; ++r) {
            ts[r] = acc41[r] + bi[r];
            pr[r] = tph[r] + lam * ts[r];
        }
        *(v4f*)&outS[sample * 20 + 16] = ts;
        *(v4f*)&outP[sample * 20 + 16] = pr;
        *(v4f*)&outF[sample * 20 + 16] = tph;
    }
}

extern "C" void kernel_launch(void* const* d_in, const int* in_sizes, int n_in,
                              void* d_out, int out_size, void* d_ws, size_t ws_size,
                              hipStream_t stream)
{
    const float* history = (const float*)d_in[0];
    const float* enc_w1  = (const float*)d_in[1];
    const float* enc_b1  = (const float*)d_in[2];
    const float* enc_w2  = (const float*)d_in[3];
    const float* enc_b2  = (const float*)d_in[4];
    const float* cor_w1  = (const float*)d_in[5];
    const float* cor_b1  = (const float*)d_in[6];
    const float* cor_w2  = (const float*)d_in[7];
    const float* cor_b2  = (const float*)d_in[8];
    const float* alpha   = (const float*)d_in[9];
    const float* beta    = (const float*)d_in[10];
    const float* gamma   = (const float*)d_in[11];
    /* d_in[12] = tau, unused (TAU_INT compile-time) */
    const float* lmix    = (const float*)d_in[13];

    prep_kernel<<<105, 256, 0, stream>>>(enc_w1, enc_w2, cor_w1, cor_w2,
                                         alpha, beta, gamma, lmix,
                                         (unsigned char*)d_ws);
    fused_kernel<<<NROWS / 64, 256, 0, stream>>>(history, enc_b1, enc_b2, cor_b1, cor_b2,
                                                 (const unsigned char*)d_ws, (float*)d_out);
}

// Round 8
// 208.211 us; speedup vs baseline: 1.0040x; 1.0040x over previous
//
#include <hip/hip_runtime.h>
#include <hip/hip_bf16.h>

// Problem constants
#define NROWS 262144
#define HISTC 24
#define FOREC 20

// MFMA fragment vector types (gfx950 16x16x32 bf16: v8bf16 in, v4f32 acc)
typedef __bf16        v8bf __attribute__((ext_vector_type(8)));
typedef float         v4f  __attribute__((ext_vector_type(4)));
typedef float         v2f  __attribute__((ext_vector_type(2)));
typedef unsigned int  v4u  __attribute__((ext_vector_type(4)));
typedef unsigned int  v2u  __attribute__((ext_vector_type(2)));

// Workspace layout (bytes): [0..16) scalars a,b,g,lam ; then swizzled bf16 weights.
// Swizzle: block (ntile,ktile) of 64 lanes x 8 bf16, elem ((nt*KT+kt)*64 + lane)*8 + j
// holding W^T[feat = nt*16 + (lane&15)][k = kt*32 + (lane>>4)*8 + j]  (OOB -> 0).
// WT4 is REPLICATED to 16 nt-slots (real nt = slot&1) so the generic cross-layer
// prefetch index ((w*4+ft)*8+kt) is valid for layer 4 too.
#define WS_WT1_OFF 64
#define WT1_ELEMS 16384    /* 16 nt * 2 kt * 512 */
#define WT2_ELEMS 65536    /* 16 nt * 8 kt * 512 */
#define WT3_ELEMS 65536
#define WT4R_ELEMS 65536   /* 16 nt-slots (real nt = slot&1) * 8 kt * 512 */

// 2*log2(e): tanh(y) = 1 - 2/(exp2(y*2log2e)+1)
#define TANH_C 2.885390081777927f

__device__ __forceinline__ unsigned short f2bf(float x) {
    unsigned u = __builtin_bit_cast(unsigned, x);
    u += 0x7FFFu + ((u >> 16) & 1u);          // round-to-nearest-even
    return (unsigned short)(u >> 16);
}

// pack two fp32 -> bf16x2 with round-half-up: 2 adds + 1 v_perm.
__device__ __forceinline__ unsigned packbf2(float a, float b) {
    unsigned ua = __builtin_bit_cast(unsigned, a) + 0x8000u;
    unsigned ub = __builtin_bit_cast(unsigned, b) + 0x8000u;
    return __builtin_amdgcn_perm(ub, ua, 0x07060302u);
}

// Barrier with LDS-visibility only: does NOT drain vmcnt, so in-flight global
// (weight-prefetch) loads survive the barrier.
__device__ __forceinline__ void lds_barrier() {
    asm volatile("s_waitcnt lgkmcnt(0)\n\ts_barrier" ::: "memory");
}

// ---------------- prep v2: coalesced transpose/convert/swizzle ----------------
// One wave per 512-elem output block (416 blocks total). The wave reads its
// 32(k) x 16(feat) fp32 source tile in 8 fully-coalesced passes (4 rows x 16
// feats per pass, 16-lane 64B segments), bounces through a padded LDS tile,
// and writes one global_store_dwordx4 per lane in fragment order.
// Old version read with 1KB per-lane stride (100% uncoalesced) and was the
// hidden ~75us in the bench total.
__global__ __launch_bounds__(256) void prep_kernel(
        const float* __restrict__ w1, const float* __restrict__ w2,
        const float* __restrict__ w3, const float* __restrict__ w4,
        const float* __restrict__ alpha, const float* __restrict__ beta,
        const float* __restrict__ gamma, const float* __restrict__ lmix,
        unsigned char* __restrict__ ws)
{
    __shared__ unsigned short tile[4][32 * 17];   // row stride 17: bank-spread
    if (blockIdx.x == 104) {                      // scalar block
        int t = threadIdx.x;
        float* wsf = (float*)ws;
        if (t == 0) wsf[0] = 1.0f / (1.0f + expf(-alpha[0]));
        else if (t == 1) wsf[1] = 1.0f / (1.0f + expf(-beta[0]));
        else if (t == 2) wsf[2] = fabsf(gamma[0]);
        else if (t == 3) wsf[3] = 1.0f / (1.0f + expf(-lmix[0]));
        return;
    }
    const int w    = threadIdx.x >> 6;
    const int lane = threadIdx.x & 63;
    const int g    = blockIdx.x * 4 + w;          // 0..415 output block id
    const float* src; int srcN, Kreal, Nreal, nt, kt;
    if (g < 32)       { src = w1; srcN = 256; Kreal = 44;  Nreal = 256; nt = g >> 1;  kt = g & 1; }
    else if (g < 160) { int t = g - 32;  src = w2; srcN = 256; Kreal = 256; Nreal = 256; nt = t >> 3; kt = t & 7; }
    else if (g < 288) { int t = g - 160; src = w3; srcN = 256; Kreal = 256; Nreal = 256; nt = t >> 3; kt = t & 7; }
    else              { int t = g - 288; src = w4; srcN = 20;  Kreal = 256; Nreal = 20;  nt = (t >> 3) & 1; kt = t & 7; }

    const int kbase = kt * 32;
    const int fl = lane & 15;                     // feat offset within tile
    const int rl = lane >> 4;                     // row sub-index (0..3)
    const int feat = nt * 16 + fl;
    unsigned short* tl = tile[w];

#pragma unroll
    for (int it = 0; it < 8; ++it) {              // 8 coalesced passes
        int row = it * 4 + rl;                    // 0..31
        int k = kbase + row;
        float v = (k < Kreal && feat < Nreal) ? src[k * srcN + feat] : 0.0f;
        tl[row * 17 + fl] = f2bf(v);
    }
    __syncthreads();                              // cheap; prep is tiny

    const int qq = lane >> 4;
    unsigned short e0 = tl[(qq * 8 + 0) * 17 + fl];
    unsigned short e1 = tl[(qq * 8 + 1) * 17 + fl];
    unsigned short e2 = tl[(qq * 8 + 2) * 17 + fl];
    unsigned short e3 = tl[(qq * 8 + 3) * 17 + fl];
    unsigned short e4 = tl[(qq * 8 + 4) * 17 + fl];
    unsigned short e5 = tl[(qq * 8 + 5) * 17 + fl];
    unsigned short e6 = tl[(qq * 8 + 6) * 17 + fl];
    unsigned short e7 = tl[(qq * 8 + 7) * 17 + fl];
    v4u pk;
    pk[0] = e0 | ((unsigned)e1 << 16);
    pk[1] = e2 | ((unsigned)e3 << 16);
    pk[2] = e4 | ((unsigned)e5 << 16);
    pk[3] = e6 | ((unsigned)e7 << 16);
    unsigned short* dst = (unsigned short*)(ws + WS_WT1_OFF);
    *(v4u*)&dst[(g * 64 + lane) * 8] = pk;
}

// ---------------- fused main kernel (unchanged from round 7) ----------------
// 4 waves, 64 samples/block. Wave w: 4 ftiles (features w*64..+63) x 4 stiles.
// Weight frags pipelined distance-1 through a 2-slot buffer A[2][4]; every layer
// enters with its kt0 frags in slot 0; the last kt iteration prefetches the NEXT
// layer's kt0, in flight across tanh + both lgkm-only barriers.
template<int KT, int KTN>
__device__ __forceinline__ void layer_pipe(unsigned short* buf,
        const v4u* __restrict__ wp, const v4u* __restrict__ wpn,
        const float* __restrict__ bias, v4u A[2][4],
        int w, int c, int q, int lane)
{
    v4f acc[4][4];
#pragma unroll
    for (int ft = 0; ft < 4; ++ft)
#pragma unroll
        for (int st = 0; st < 4; ++st) {
            v4f z = {0.0f, 0.0f, 0.0f, 0.0f};
            acc[ft][st] = z;
        }

#pragma unroll
    for (int kt = 0; kt < KT; ++kt) {
        const int cs = kt & 1;
        const int ps = cs ^ 1;
        if (kt + 1 < KT) {
#pragma unroll
            for (int ft = 0; ft < 4; ++ft)
                A[ps][ft] = wp[((w * 4 + ft) * KT + kt + 1) * 64 + lane];
        } else {   // prefetch next layer's kt0
#pragma unroll
            for (int ft = 0; ft < 4; ++ft)
                A[ps][ft] = wpn[((w * 4 + ft) * KTN + 0) * 64 + lane];
        }
#pragma unroll
        for (int st = 0; st < 4; ++st) {
            v4u braw = *(const v4u*)&buf[(st * 16 + c) * 264 + kt * 32 + q * 8];
            v8bf bb = __builtin_bit_cast(v8bf, braw);
#pragma unroll
            for (int ft = 0; ft < 4; ++ft)
                acc[ft][st] = __builtin_amdgcn_mfma_f32_16x16x32_bf16(
                    __builtin_bit_cast(v8bf, A[cs][ft]), bb, acc[ft][st], 0, 0, 0);
        }
    }

    lds_barrier();   // all reads done before in-place overwrite (vmcnt NOT drained)

    // Epilogue: lane (q,c) holds sample c, features base+q*4..+3 per tile.
#pragma unroll
    for (int ft = 0; ft < 4; ++ft) {
        v4f bi = *(const v4f*)&bias[w * 64 + ft * 16 + q * 4];
        v4f bic;
#pragma unroll
        for (int r = 0; r < 4; ++r) bic[r] = bi[r] * TANH_C;
#pragma unroll
        for (int st = 0; st < 4; ++st) {
            float x[4];
#pragma unroll
            for (int r = 0; r < 4; ++r) {
                float t = __builtin_fmaf(acc[ft][st][r], TANH_C, bic[r]);
                float p = __builtin_amdgcn_exp2f(t);
                float rc = __builtin_amdgcn_rcpf(p + 1.0f);
                x[r] = __builtin_fmaf(-2.0f, rc, 1.0f);
            }
            v2u d; d[0] = packbf2(x[0], x[1]); d[1] = packbf2(x[2], x[3]);
            *(v2u*)&buf[(st * 16 + c) * 264 + w * 64 + ft * 16 + q * 4] = d;
        }
    }
    lds_barrier();
}

__global__ __launch_bounds__(256, 4) void fused_kernel(
    const float* __restrict__ history,
    const float* __restrict__ eb1, const float* __restrict__ eb2,
    const float* __restrict__ cb1, const float* __restrict__ cb2,
    const unsigned char* __restrict__ ws, float* __restrict__ out)
{
    __shared__ unsigned short buf[64 * 264];   // 33792 B, in-place act buffer
    __shared__ float tp[64 * 20];              // 5120 B fp32 T_physics

    const int tid  = threadIdx.x;
    const int w    = tid >> 6;                 // 4 waves
    const int lane = tid & 63;
    const int c    = lane & 15;
    const int q    = lane >> 4;
    const int row0 = blockIdx.x << 6;          // 64 samples per WG
    const float* wsf = (const float*)ws;
    const v4u* wp1 = (const v4u*)(ws + WS_WT1_OFF);
    const v4u* wp2 = wp1 + WT1_ELEMS / 8;
    const v4u* wp3 = wp2 + WT2_ELEMS / 8;
    const v4u* wp4 = wp3 + WT3_ELEMS / 8;

    // Preload layer-1 kt0 frags into slot 0 BEFORE staging (overlaps L2 latency).
    v4u A[2][4];
#pragma unroll
    for (int ft = 0; ft < 4; ++ft)
        A[0][ft] = wp1[((w * 4 + ft) * 2 + 0) * 64 + lane];

    // --- staging: global float4 -> bf16x4 pack in regs -> one ds_write_b64 ---
#pragma unroll
    for (int i = 0; i < 2; ++i) {
        int e = tid + i * 256;
        if (e < 384) {
            int r  = e / 6, c4 = e - r * 6;
            v4f h4 = *(const v4f*)&history[(long)(row0 + r) * 24 + c4 * 4];
            v2u d; d[0] = packbf2(h4[0], h4[1]); d[1] = packbf2(h4[2], h4[3]);
            *(v2u*)&buf[r * 264 + c4 * 4] = d;
        }
    }
    // zero-fill cols 44..63 (pad vs stale LDS): 64 rows x 5 b64-groups = 320 tasks
#pragma unroll
    for (int i = 0; i < 2; ++i) {
        int e = tid + i * 256;
        if (e < 320) {
            int r = e / 5, g = e - r * 5;
            v2u z = {0u, 0u};
            *(v2u*)&buf[r * 264 + 44 + g * 4] = z;
        }
    }
    // physics: one thread per row; last-6 history read direct from global (L2-hot)
    if (tid < 64) {
        const float* hrow = &history[(long)(row0 + tid) * 24];
        v2f h18 = *(const v2f*)&hrow[18];
        v4f h20 = *(const v4f*)&hrow[20];
        float pa = wsf[0], pb = wsf[1], pg = wsf[2];
        float d0 = h18[0], d1 = h18[1], d2 = h20[0];
        float d3 = h20[1], d4 = h20[2], d5 = h20[3];
        float T = d5;
#pragma unroll
        for (int s = 0; s < 20; ++s) {
            float t3 = T * T * T;
            float Tn = T - pa * T;
            Tn = Tn - pb * d0;
            Tn = Tn - pg * t3;
            tp[tid * 20 + s] = Tn;
            buf[tid * 264 + 24 + s] = f2bf(Tn);
            d0 = d1; d1 = d2; d2 = d3; d3 = d4; d4 = d5; d5 = Tn;
            T = Tn;
        }
    }
    lds_barrier();

    layer_pipe<2, 8>(buf, wp1, wp2, eb1, A, w, c, q, lane);   // 44(pad64)->256
    layer_pipe<8, 8>(buf, wp2, wp3, eb2, A, w, c, q, lane);   // 256->256
    layer_pipe<8, 8>(buf, wp3, wp4, cb1, A, w, c, q, lane);   // 256->256

    // Layer 4: 256 -> 20. Wave w = stile w. Slot 0 holds wp4 kt0 frags
    // (replicated wt4: slot index w*4+ft has real nt = (w*4+ft)&1 = ft&1).
    v4f acc40 = {0.0f, 0.0f, 0.0f, 0.0f}, acc41 = {0.0f, 0.0f, 0.0f, 0.0f};
#pragma unroll
    for (int kt = 0; kt < 8; ++kt) {
        const int cs = kt & 1, ps = cs ^ 1;
        if (kt + 1 < 8) {
            A[ps][0] = wp4[((w * 4 + 0) * 8 + kt + 1) * 64 + lane];
            A[ps][1] = wp4[((w * 4 + 1) * 8 + kt + 1) * 64 + lane];
        }
        v4u braw = *(const v4u*)&buf[(w * 16 + c) * 264 + kt * 32 + q * 8];
        v8bf bb = __builtin_bit_cast(v8bf, braw);
        acc40 = __builtin_amdgcn_mfma_f32_16x16x32_bf16(
            __builtin_bit_cast(v8bf, A[cs][0]), bb, acc40, 0, 0, 0);
        acc41 = __builtin_amdgcn_mfma_f32_16x16x32_bf16(
            __builtin_bit_cast(v8bf, A[cs][1]), bb, acc41, 0, 0, 0);
    }

    const float lam = wsf[3];
    const long sample = (long)row0 + w * 16 + c;
    float* outP = out;                         // T_pred
    float* outF = out + (long)NROWS * 20;      // T_physics
    float* outS = out + (long)NROWS * 40;      // T_soft
    {   // ftile 0: features q*4..q*4+3, all valid (<20)
        int f0 = q * 4;
        v4f bi  = *(const v4f*)&cb2[f0];
        v4f tph = *(const v4f*)&tp[(w * 16 + c) * 20 + f0];
        v4f ts, pr;
#pragma unroll
        for (int r = 0; r < 4; ++r) {
            ts[r] = acc40[r] + bi[r];
            pr[r] = tph[r] + lam * ts[r];
        }
        *(v4f*)&outS[sample * 20 + f0] = ts;
        *(v4f*)&outP[sample * 20 + f0] = pr;
        *(v4f*)&outF[sample * 20 + f0] = tph;
    }
    if (q == 0) {  // ftile 1: features 16..19 valid only for q==0
        v4f bi  = *(const v4f*)&cb2[16];
        v4f tph = *(const v4f*)&tp[(w * 16 + c) * 20 + 16];
        v4f ts, pr;
#pragma unroll
        for (int r = 0; r < 4; ++r) {
            ts[r] = acc41[r] + bi[r];
            pr[r] = tph[r] + lam * ts[r];
        }
        *(v4f*)&outS[sample * 20 + 16] = ts;
        *(v4f*)&outP[sample * 20 + 16] = pr;
        *(v4f*)&outF[sample * 20 + 16] = tph;
    }
}

extern "C" void kernel_launch(void* const* d_in, const int* in_sizes, int n_in,
                              void* d_out, int out_size, void* d_ws, size_t ws_size,
                              hipStream_t stream)
{
    const float* history = (const float*)d_in[0];
    const float* enc_w1  = (const float*)d_in[1];
    const float* enc_b1  = (const float*)d_in[2];
    const float* enc_w2  = (const float*)d_in[3];
    const float* enc_b2  = (const float*)d_in[4];
    const float* cor_w1  = (const float*)d_in[5];
    const float* cor_b1  = (const float*)d_in[6];
    const float* cor_w2  = (const float*)d_in[7];
    const float* cor_b2  = (const float*)d_in[8];
    const float* alpha   = (const float*)d_in[9];
    const float* beta    = (const float*)d_in[10];
    const float* gamma   = (const float*)d_in[11];
    /* d_in[12] = tau, unused (TAU_INT compile-time) */
    const float* lmix    = (const float*)d_in[13];

    prep_kernel<<<105, 256, 0, stream>>>(enc_w1, enc_w2, cor_w1, cor_w2,
                                         alpha, beta, gamma, lmix,
                                         (unsigned char*)d_ws);
    fused_kernel<<<NROWS / 64, 256, 0, stream>>>(history, enc_b1, enc_b2, cor_b1, cor_b2,
                                                 (const unsigned char*)d_ws, (float*)d_out);
}